// Round 1
// 20187.178 us; speedup vs baseline: 1.0492x; 1.0492x over previous
//
#include <hip/hip_runtime.h>
#include <hip/hip_cooperative_groups.h>

// LSTM_71167608094989: 2-layer LSTM, T=512, B=64, I=H=1024, eval mode.
// Round 2: single persistent cooperative kernel. 256 blocks (1/CU) x 256 thr.
// Per block: 8 hidden units (32 gate-cols) x K=2048 weight slice resident in
// 128 KB LDS for all 512 steps; c-state in registers; one grid.sync per
// super-step (diagonal pipeline: layer0 step s + layer1 step s-1).

typedef _Float16 h8_t __attribute__((ext_vector_type(8)));
typedef _Float16 h4_t __attribute__((ext_vector_type(4)));
typedef float f4_t __attribute__((ext_vector_type(4)));

#define T_STEPS 512
#define BATCH 64
#define HID 1024
#define STEP_ELEMS (BATCH * HID)   // 65536

// ---------------- conversion kernels ----------------

__global__ void k_f32_to_f16(const float* __restrict__ src, _Float16* __restrict__ dst) {
    size_t i = ((size_t)blockIdx.x * blockDim.x + threadIdx.x) * 4;
    float4 v = *(const float4*)(src + i);
    h4_t h = { (_Float16)v.x, (_Float16)v.y, (_Float16)v.z, (_Float16)v.w };
    *(h4_t*)(dst + i) = h;
}

// wcat[n][k], n in [0,4096), k in [0,2048): k<1024 -> w_ih[n][k], else w_hh[n][k-1024]
__global__ void k_build_wcat(const float* __restrict__ w_ih, const float* __restrict__ w_hh,
                             _Float16* __restrict__ wcat) {
    size_t i = ((size_t)blockIdx.x * blockDim.x + threadIdx.x) * 4;
    int n = (int)(i >> 11);
    int k = (int)(i & 2047);
    const float* src = (k < 1024) ? (w_ih + (size_t)n * 1024 + k)
                                  : (w_hh + (size_t)n * 1024 + (k - 1024));
    float4 v = *(const float4*)src;
    h4_t h = { (_Float16)v.x, (_Float16)v.y, (_Float16)v.z, (_Float16)v.w };
    *(h4_t*)(wcat + i) = h;
}

__global__ void k_bias(const float* __restrict__ a, const float* __restrict__ b,
                       float* __restrict__ o) {
    int i = blockIdx.x * blockDim.x + threadIdx.x;
    o[i] = a[i] + b[i];
}

__device__ __forceinline__ float sigmf(float x) { return 1.0f / (1.0f + __expf(-x)); }

// ---------------- persistent cooperative kernel ----------------
// grid = 256 blocks x 256 threads, dynamic LDS = 128 KB (weight slice).
// block b<128: layer0, units u0=b*8..+8 ; b>=128: layer1.
// 32 gate-cols per block, col C: gate = C>>3 (i,f,g,o), unit = u0+(C&7).
// LDS layout: [kk 0..63][C 0..31][32 halves] -> byte = kk*2048 + C*64 + (k%32)*2
// Wave w: batch rows 16w..16w+15; 2 N-tiles (C 0..15 / 16..31); K loop 64 kk.

__global__ __launch_bounds__(256, 1) void lstm_persist(
    const _Float16* __restrict__ x16, _Float16* __restrict__ h1,
    _Float16* __restrict__ h2, float* __restrict__ out,
    const _Float16* __restrict__ wc0, const _Float16* __restrict__ wc1,
    const float* __restrict__ bias0, const float* __restrict__ bias1)
{
    extern __shared__ char smem[];
    const int blk = blockIdx.x;
    const int layer = blk >> 7;
    const int u0 = (blk & 127) * 8;
    const _Float16* __restrict__ wc = layer ? wc1 : wc0;
    const float* __restrict__ bias = layer ? bias1 : bias0;
    const int tid = threadIdx.x;

    // one-time: weight slice -> LDS (coalesced 4KB row sweeps)
    {
        const int kk = tid >> 2, qq = tid & 3;
#pragma unroll 4
        for (int C = 0; C < 32; ++C) {
            const int n = ((C >> 3) << 10) + u0 + (C & 7);
            h8_t v = *(const h8_t*)(wc + (size_t)n * 2048 + kk * 32 + qq * 8);
            *(h8_t*)(smem + kk * 2048 + C * 64 + qq * 16) = v;
        }
    }
    __syncthreads();

    const int lane = tid & 63;
    const int wave = tid >> 6;
    const int q = lane >> 4;       // k-quad within 32-wide k-step
    const int m16 = lane & 15;     // col-in-tile (B) / row-in-tile (A)
    const int unit = u0 + (m16 & 7);
    const bool lo8 = (m16 & 8) == 0;   // holds gates i(t0),g(t1); partner holds f,o

    const float bi = bias[unit];
    const float bf = bias[1024 + unit];
    const float bg = bias[2048 + unit];
    const float bo = bias[3072 + unit];

    const char* __restrict__ lb = smem + m16 * 64 + q * 16;  // + kk*2048 (+1024 tile1)
    const int aoff = (wave * 16 + m16) * 1024 + q * 8;       // A element offset

    float cst[4] = {0.f, 0.f, 0.f, 0.f};  // cell state (redundant across lane pair)

    cooperative_groups::grid_group grid = cooperative_groups::this_grid();

    for (int s = 0; s <= T_STEPS; ++s) {
        if (s) grid.sync();   // all blocks, every iteration
        const bool active = layer ? (s >= 1) : (s < T_STEPS);
        if (!active) continue;
        const int t = layer ? (s - 1) : s;
        const _Float16* __restrict__ src1 =
            layer ? (h1 + (size_t)t * STEP_ELEMS) : (x16 + (size_t)t * STEP_ELEMS);
        const _Float16* __restrict__ src2 = (t > 0)
            ? (layer ? (h2 + (size_t)(t - 1) * STEP_ELEMS)
                     : (h1 + (size_t)(t - 1) * STEP_ELEMS))
            : nullptr;

        f4_t acc0 = {0.f, 0.f, 0.f, 0.f};
        f4_t acc1 = {0.f, 0.f, 0.f, 0.f};

        // phase 1: k in [0,1024) — x-input (layer0) / h1[t] (layer1)
        {
            h8_t areg[32];
#pragma unroll
            for (int kk = 0; kk < 32; ++kk)
                areg[kk] = *(const h8_t*)(src1 + aoff + kk * 32);
#pragma unroll
            for (int kk = 0; kk < 32; ++kk) {
                h8_t b0 = *(const h8_t*)(lb + kk * 2048);
                h8_t b1 = *(const h8_t*)(lb + kk * 2048 + 1024);
                acc0 = __builtin_amdgcn_mfma_f32_16x16x32_f16(areg[kk], b0, acc0, 0, 0, 0);
                acc1 = __builtin_amdgcn_mfma_f32_16x16x32_f16(areg[kk], b1, acc1, 0, 0, 0);
            }
        }
        // phase 2: k in [1024,2048) — h_prev (zero at first step: skipped)
        if (src2) {
            h8_t areg[32];
#pragma unroll
            for (int kk = 0; kk < 32; ++kk)
                areg[kk] = *(const h8_t*)(src2 + aoff + kk * 32);
#pragma unroll
            for (int kk = 0; kk < 32; ++kk) {
                h8_t b0 = *(const h8_t*)(lb + 65536 + kk * 2048);
                h8_t b1 = *(const h8_t*)(lb + 65536 + kk * 2048 + 1024);
                acc0 = __builtin_amdgcn_mfma_f32_16x16x32_f16(areg[kk], b0, acc0, 0, 0, 0);
                acc1 = __builtin_amdgcn_mfma_f32_16x16x32_f16(areg[kk], b1, acc1, 0, 0, 0);
            }
        }

        // epilogue: lane pair (m16, m16^8) exchange to assemble i,f,g,o per unit.
        _Float16* __restrict__ hout = (layer ? h2 : h1) + (size_t)t * STEP_ELEMS;
        float* __restrict__ oout = layer ? (out + (size_t)t * STEP_ELEMS) : nullptr;
#pragma unroll
        for (int ri = 0; ri < 4; ++ri) {
            const float p0 = __shfl_xor(acc0[ri], 8, 64);
            const float p1 = __shfl_xor(acc1[ri], 8, 64);
            const float iv = (lo8 ? acc0[ri] : p0) + bi;
            const float fv = (lo8 ? p0 : acc0[ri]) + bf;
            const float gv = (lo8 ? acc1[ri] : p1) + bg;
            const float ov = (lo8 ? p1 : acc1[ri]) + bo;
            const float cn = sigmf(fv) * cst[ri] + sigmf(iv) * tanhf(gv);
            const float hn = sigmf(ov) * tanhf(cn);
            cst[ri] = cn;
            if (lo8) {
                const size_t idx = (size_t)((wave * 16 + q * 4 + ri) * HID + unit);
                hout[idx] = (_Float16)hn;
                if (oout) oout[idx] = hn;
            }
        }
    }
}

// ---------------- fallback per-step kernel (previous round, kept as safety) ----------------

__global__ __launch_bounds__(256) void lstm_step2(
    const _Float16* __restrict__ xin0, const _Float16* __restrict__ hp0,
    const _Float16* __restrict__ wc0, const float* __restrict__ bb0,
    float* __restrict__ cb0, _Float16* __restrict__ ho0,
    const _Float16* __restrict__ xin1, const _Float16* __restrict__ hp1,
    const _Float16* __restrict__ wc1, const float* __restrict__ bb1,
    float* __restrict__ cb1, _Float16* __restrict__ ho1,
    float* __restrict__ of1, int mask)
{
    int blk = blockIdx.x;
    const _Float16 *xin, *hp, *wc;
    const float* bb;
    float* cbuf;
    _Float16* hf;
    float* hf32 = nullptr;
    int u0;
    if (blk < 64) {
        if (!(mask & 1)) return;
        xin = xin0; hp = hp0; wc = wc0; bb = bb0; cbuf = cb0; hf = ho0;
        u0 = blk * 16;
    } else {
        if (!(mask & 2)) return;
        xin = xin1; hp = hp1; wc = wc1; bb = bb1; cbuf = cb1; hf = ho1;
        hf32 = of1;
        u0 = (blk - 64) * 16;
    }

    const int lane = threadIdx.x & 63;
    const int wave = threadIdx.x >> 6;
    const int q = lane >> 4;
    const int m16 = lane & 15;
    const int r = wave * 16 + m16;

    f4_t acc[4] = {};
    const _Float16* wrow[4];
#pragma unroll
    for (int g = 0; g < 4; ++g)
        wrow[g] = wc + (size_t)(g * 1024 + u0 + m16) * 2048 + q * 8;

    {
        const _Float16* arow = xin + (size_t)r * 1024 + q * 8;
#pragma unroll 4
        for (int kk = 0; kk < 32; ++kk) {
            h8_t a = *(const h8_t*)(arow + kk * 32);
#pragma unroll
            for (int g = 0; g < 4; ++g) {
                h8_t b = *(const h8_t*)(wrow[g] + kk * 32);
                acc[g] = __builtin_amdgcn_mfma_f32_16x16x32_f16(a, b, acc[g], 0, 0, 0);
            }
        }
    }
    {
        const _Float16* arow = hp + (size_t)r * 1024 + q * 8;
#pragma unroll 4
        for (int kk = 0; kk < 32; ++kk) {
            h8_t a = *(const h8_t*)(arow + kk * 32);
#pragma unroll
            for (int g = 0; g < 4; ++g) {
                h8_t b = *(const h8_t*)(wrow[g] + 1024 + kk * 32);
                acc[g] = __builtin_amdgcn_mfma_f32_16x16x32_f16(a, b, acc[g], 0, 0, 0);
            }
        }
    }

    const int unit = u0 + m16;
    const float bi = bb[unit];
    const float bf = bb[1024 + unit];
    const float bg = bb[2048 + unit];
    const float bo = bb[3072 + unit];
#pragma unroll
    for (int ri = 0; ri < 4; ++ri) {
        int row = wave * 16 + q * 4 + ri;
        float iv = acc[0][ri] + bi;
        float fv = acc[1][ri] + bf;
        float gv = acc[2][ri] + bg;
        float ov = acc[3][ri] + bo;
        size_t idx = (size_t)row * HID + unit;
        float cn = sigmf(fv) * cbuf[idx] + sigmf(iv) * tanhf(gv);
        float hn = sigmf(ov) * tanhf(cn);
        cbuf[idx] = cn;
        hf[idx] = (_Float16)hn;
        if (hf32) hf32[idx] = hn;
    }
}

// ---------------- host orchestration ----------------

extern "C" void kernel_launch(void* const* d_in, const int* in_sizes, int n_in,
                              void* d_out, int out_size, void* d_ws, size_t ws_size,
                              hipStream_t stream) {
    const float* input = (const float*)d_in[0];
    const float* w_ih0 = (const float*)d_in[1];
    const float* w_hh0 = (const float*)d_in[2];
    const float* b_ih0 = (const float*)d_in[3];
    const float* b_hh0 = (const float*)d_in[4];
    const float* w_ih1 = (const float*)d_in[5];
    const float* w_hh1 = (const float*)d_in[6];
    const float* b_ih1 = (const float*)d_in[7];
    const float* b_hh1 = (const float*)d_in[8];
    float* outp = (float*)d_out;

    // workspace partition (~236 MB)
    char* p = (char*)d_ws;
    _Float16* x16 = (_Float16*)p;  p += (size_t)T_STEPS * STEP_ELEMS * 2;
    _Float16* h1  = (_Float16*)p;  p += (size_t)T_STEPS * STEP_ELEMS * 2;
    _Float16* h2  = (_Float16*)p;  p += (size_t)T_STEPS * STEP_ELEMS * 2;
    _Float16* wc0 = (_Float16*)p;  p += (size_t)4096 * 2048 * 2;
    _Float16* wc1 = (_Float16*)p;  p += (size_t)4096 * 2048 * 2;
    float* bias0  = (float*)p;     p += 4096 * 4;
    float* bias1  = (float*)p;     p += 4096 * 4;
    float* c0     = (float*)p;     p += STEP_ELEMS * 4;   // fallback only
    float* c1     = (float*)p;     p += STEP_ELEMS * 4;   // fallback only
    _Float16* hz  = (_Float16*)p;  p += STEP_ELEMS * 2;   // fallback only

    hipMemsetAsync(c0, 0, STEP_ELEMS * 4, stream);
    hipMemsetAsync(c1, 0, STEP_ELEMS * 4, stream);
    hipMemsetAsync(hz, 0, STEP_ELEMS * 2, stream);

    // conversions
    k_f32_to_f16<<<(T_STEPS * STEP_ELEMS / 4) / 256, 256, 0, stream>>>(input, x16);
    k_build_wcat<<<(4096 * 2048 / 4) / 256, 256, 0, stream>>>(w_ih0, w_hh0, wc0);
    k_build_wcat<<<(4096 * 2048 / 4) / 256, 256, 0, stream>>>(w_ih1, w_hh1, wc1);
    k_bias<<<16, 256, 0, stream>>>(b_ih0, b_hh0, bias0);
    k_bias<<<16, 256, 0, stream>>>(b_ih1, b_hh1, bias1);

    // persistent cooperative kernel: all 513 super-steps inside one launch
    void* params[] = { (void*)&x16, (void*)&h1, (void*)&h2, (void*)&outp,
                       (void*)&wc0, (void*)&wc1, (void*)&bias0, (void*)&bias1 };
    hipError_t ce = hipLaunchCooperativeKernel((const void*)lstm_persist,
                                               dim3(256), dim3(256),
                                               params, 131072u, stream);
    if (ce != hipSuccess) {
        // fallback: previous round's per-step pipeline
        for (int s = 0; s <= T_STEPS; ++s) {
            int t1 = (s > 0) ? (s - 1) : 0;
            const _Float16* xin0 = x16 + (size_t)s * STEP_ELEMS;
            const _Float16* hp0  = (s == 0) ? hz : h1 + (size_t)(s - 1) * STEP_ELEMS;
            _Float16* ho0        = h1 + (size_t)s * STEP_ELEMS;
            const _Float16* xin1 = h1 + (size_t)t1 * STEP_ELEMS;
            const _Float16* hp1  = (t1 == 0) ? hz : h2 + (size_t)(t1 - 1) * STEP_ELEMS;
            _Float16* ho1        = h2 + (size_t)t1 * STEP_ELEMS;
            float* of1           = outp + (size_t)t1 * STEP_ELEMS;
            int mask = ((s < T_STEPS) ? 1 : 0) | ((s >= 1) ? 2 : 0);
            if (s == T_STEPS) xin0 = x16;
            lstm_step2<<<128, 256, 0, stream>>>(xin0, hp0, wc0, bias0, c0, ho0,
                                                xin1, hp1, wc1, bias1, c1, ho1,
                                                of1, mask);
        }
    }
}

// Round 2
// 18338.957 us; speedup vs baseline: 1.1550x; 1.1008x over previous
//
#include <hip/hip_runtime.h>
#include <hip/hip_cooperative_groups.h>

// LSTM_71167608094989: 2-layer LSTM, T=512, B=64, I=H=1024, eval mode.
// Round 3: persistent kernel, custom decoupled barriers (grid.sync was ~37us/step).
//  - L0 blocks (0..127) free-run on counter cnt0; L1 blocks (128..255) follow via
//    cnt0 (producer progress) + cnt1 (own group barrier). Monotonic counts.
//  - Phase-1 (x / h1[t]) hoisted before the serial wait; only phase-2 on critical path.
//  - LDS B-tile XOR-swizzle: chunk(C,q) at slot (q^(C&3))*32+C -> slot%8 == C%8,
//    uniform across 16-lane service groups (was 8-way conflicted, 2.7e8 cycles).

typedef _Float16 h8_t __attribute__((ext_vector_type(8)));
typedef _Float16 h4_t __attribute__((ext_vector_type(4)));
typedef float f4_t __attribute__((ext_vector_type(4)));

#define T_STEPS 512
#define BATCH 64
#define HID 1024
#define STEP_ELEMS (BATCH * HID)   // 65536

// ---------------- conversion kernels ----------------

__global__ void k_f32_to_f16(const float* __restrict__ src, _Float16* __restrict__ dst) {
    size_t i = ((size_t)blockIdx.x * blockDim.x + threadIdx.x) * 4;
    float4 v = *(const float4*)(src + i);
    h4_t h = { (_Float16)v.x, (_Float16)v.y, (_Float16)v.z, (_Float16)v.w };
    *(h4_t*)(dst + i) = h;
}

__global__ void k_build_wcat(const float* __restrict__ w_ih, const float* __restrict__ w_hh,
                             _Float16* __restrict__ wcat) {
    size_t i = ((size_t)blockIdx.x * blockDim.x + threadIdx.x) * 4;
    int n = (int)(i >> 11);
    int k = (int)(i & 2047);
    const float* src = (k < 1024) ? (w_ih + (size_t)n * 1024 + k)
                                  : (w_hh + (size_t)n * 1024 + (k - 1024));
    float4 v = *(const float4*)src;
    h4_t h = { (_Float16)v.x, (_Float16)v.y, (_Float16)v.z, (_Float16)v.w };
    *(h4_t*)(wcat + i) = h;
}

__global__ void k_bias(const float* __restrict__ a, const float* __restrict__ b,
                       float* __restrict__ o) {
    int i = blockIdx.x * blockDim.x + threadIdx.x;
    o[i] = a[i] + b[i];
}

__device__ __forceinline__ float sigmf(float x) { return 1.0f / (1.0f + __expf(-x)); }
__device__ __forceinline__ float tanh_fast(float x) {
    x = fminf(fmaxf(x, -15.f), 15.f);
    float e = __expf(2.f * x);
    return (e - 1.f) / (e + 1.f);
}

// ---------------- barrier primitives (device-scope, monotonic counters) -------

__device__ __forceinline__ void bar_arrive(unsigned* cnt) {
    // every thread: drain own stores to device scope, then one add per block
    __builtin_amdgcn_fence(__ATOMIC_RELEASE, "agent");
    __syncthreads();
    if (threadIdx.x == 0)
        __hip_atomic_fetch_add(cnt, 1u, __ATOMIC_RELAXED, __HIP_MEMORY_SCOPE_AGENT);
}

__device__ __forceinline__ void bar_wait(const unsigned* cnt, unsigned target) {
    if (threadIdx.x == 0) {
        while (__hip_atomic_load(cnt, __ATOMIC_RELAXED, __HIP_MEMORY_SCOPE_AGENT) < target)
            __builtin_amdgcn_s_sleep(1);
    }
    __syncthreads();
    __builtin_amdgcn_fence(__ATOMIC_ACQUIRE, "agent");
}

// ---------------- persistent kernel ----------------
// grid = 256 blocks x 256 threads, dynamic LDS = 128 KB (swizzled weight slice).
// block b<128: layer0 units u0=b*8 ; b>=128: layer1 units u0=(b-128)*8.
// LDS: 64 kk-blocks x 128 chunks(16B). chunk(C,q) of kk at
//   kk*2048 + ((q^(C&3))*32 + C)*16.  Read: lane(q,m16) col m16 -> +0, col m16+16 -> +256.

__device__ __forceinline__ void do_phase(f4_t& a0, f4_t& a1,
                                         const _Float16* __restrict__ src, int aoff,
                                         const char* __restrict__ lb, int lds_base) {
    h8_t areg[32];
#pragma unroll
    for (int kk = 0; kk < 32; ++kk)
        areg[kk] = *(const h8_t*)(src + aoff + kk * 32);
#pragma unroll
    for (int kk = 0; kk < 32; ++kk) {
        h8_t b0 = *(const h8_t*)(lb + lds_base + kk * 2048);
        h8_t b1 = *(const h8_t*)(lb + lds_base + kk * 2048 + 256);
        a0 = __builtin_amdgcn_mfma_f32_16x16x32_f16(areg[kk], b0, a0, 0, 0, 0);
        a1 = __builtin_amdgcn_mfma_f32_16x16x32_f16(areg[kk], b1, a1, 0, 0, 0);
    }
}

__global__ __launch_bounds__(256, 1) void lstm_persist(
    const _Float16* __restrict__ x16, _Float16* __restrict__ h1,
    _Float16* __restrict__ h2, float* __restrict__ out,
    const _Float16* __restrict__ wc0, const _Float16* __restrict__ wc1,
    const float* __restrict__ bias0, const float* __restrict__ bias1,
    unsigned* __restrict__ cnt0, unsigned* __restrict__ cnt1)
{
    extern __shared__ char smem[];
    const int blk = blockIdx.x;
    const int layer = blk >> 7;
    const int u0 = (blk & 127) * 8;
    const _Float16* __restrict__ wc = layer ? wc1 : wc0;
    const float* __restrict__ bias = layer ? bias1 : bias0;
    const int tid = threadIdx.x;

    // one-time staging: coalesced global reads, swizzled LDS writes
    {
        const int kk = tid >> 2, qq = tid & 3;   // kk 0..63, qq 0..3
#pragma unroll 4
        for (int C = 0; C < 32; ++C) {
            const int n = ((C >> 3) << 10) + u0 + (C & 7);
            h8_t v = *(const h8_t*)(wc + (size_t)n * 2048 + (size_t)kk * 32 + qq * 8);
            const int p = qq ^ (C & 3);
            *(h8_t*)(smem + kk * 2048 + p * 512 + C * 16) = v;
        }
    }
    __syncthreads();

    const int lane = tid & 63;
    const int wave = tid >> 6;
    const int q = lane >> 4;
    const int m16 = lane & 15;
    const int unit = u0 + (m16 & 7);
    const bool lo8 = (m16 & 8) == 0;

    const float bi = bias[unit];
    const float bf = bias[1024 + unit];
    const float bg = bias[2048 + unit];
    const float bo = bias[3072 + unit];

    const char* __restrict__ lb = smem + ((q ^ (m16 & 3)) * 512 + m16 * 16);
    const int aoff = (wave * 16 + m16) * 1024 + q * 8;

    float cst[4] = {0.f, 0.f, 0.f, 0.f};

    if (layer == 0) {
        for (int s = 0; s < T_STEPS; ++s) {
            f4_t acc0 = {0.f, 0.f, 0.f, 0.f};
            f4_t acc1 = {0.f, 0.f, 0.f, 0.f};
            // phase 1: x[s] — static, computed before the serial wait
            do_phase(acc0, acc1, x16 + (size_t)s * STEP_ELEMS, aoff, lb, 0);
            if (s) {
                bar_wait(cnt0, 128u * (unsigned)s);   // h1[s-1] complete
                do_phase(acc0, acc1, h1 + (size_t)(s - 1) * STEP_ELEMS, aoff, lb, 65536);
            }
            _Float16* __restrict__ hout = h1 + (size_t)s * STEP_ELEMS;
#pragma unroll
            for (int ri = 0; ri < 4; ++ri) {
                const float p0 = __shfl_xor(acc0[ri], 8, 64);
                const float p1 = __shfl_xor(acc1[ri], 8, 64);
                const float iv = (lo8 ? acc0[ri] : p0) + bi;
                const float fv = (lo8 ? p0 : acc0[ri]) + bf;
                const float gv = (lo8 ? acc1[ri] : p1) + bg;
                const float ov = (lo8 ? p1 : acc1[ri]) + bo;
                const float cn = sigmf(fv) * cst[ri] + sigmf(iv) * tanh_fast(gv);
                const float hn = sigmf(ov) * tanh_fast(cn);
                cst[ri] = cn;
                if (lo8) {
                    const size_t idx = (size_t)((wave * 16 + q * 4 + ri) * HID + unit);
                    hout[idx] = (_Float16)hn;
                }
            }
            bar_arrive(cnt0);
        }
    } else {
        for (int t = 0; t < T_STEPS; ++t) {
            f4_t acc0 = {0.f, 0.f, 0.f, 0.f};
            f4_t acc1 = {0.f, 0.f, 0.f, 0.f};
            bar_wait(cnt0, 128u * (unsigned)(t + 1));   // h1[t] ready (L0 runs ahead)
            do_phase(acc0, acc1, h1 + (size_t)t * STEP_ELEMS, aoff, lb, 0);
            if (t) {
                bar_wait(cnt1, 128u * (unsigned)t);     // h2[t-1] complete
                do_phase(acc0, acc1, h2 + (size_t)(t - 1) * STEP_ELEMS, aoff, lb, 65536);
            }
            _Float16* __restrict__ hout = h2 + (size_t)t * STEP_ELEMS;
            float* __restrict__ oout = out + (size_t)t * STEP_ELEMS;
#pragma unroll
            for (int ri = 0; ri < 4; ++ri) {
                const float p0 = __shfl_xor(acc0[ri], 8, 64);
                const float p1 = __shfl_xor(acc1[ri], 8, 64);
                const float iv = (lo8 ? acc0[ri] : p0) + bi;
                const float fv = (lo8 ? p0 : acc0[ri]) + bf;
                const float gv = (lo8 ? acc1[ri] : p1) + bg;
                const float ov = (lo8 ? p1 : acc1[ri]) + bo;
                const float cn = sigmf(fv) * cst[ri] + sigmf(iv) * tanh_fast(gv);
                const float hn = sigmf(ov) * tanh_fast(cn);
                cst[ri] = cn;
                if (lo8) {
                    const size_t idx = (size_t)((wave * 16 + q * 4 + ri) * HID + unit);
                    hout[idx] = (_Float16)hn;
                    oout[idx] = hn;
                }
            }
            bar_arrive(cnt1);
        }
    }
}

// ---------------- fallback per-step kernel (safety) ----------------

__global__ __launch_bounds__(256) void lstm_step2(
    const _Float16* __restrict__ xin0, const _Float16* __restrict__ hp0,
    const _Float16* __restrict__ wc0, const float* __restrict__ bb0,
    float* __restrict__ cb0, _Float16* __restrict__ ho0,
    const _Float16* __restrict__ xin1, const _Float16* __restrict__ hp1,
    const _Float16* __restrict__ wc1, const float* __restrict__ bb1,
    float* __restrict__ cb1, _Float16* __restrict__ ho1,
    float* __restrict__ of1, int mask)
{
    int blk = blockIdx.x;
    const _Float16 *xin, *hp, *wc;
    const float* bb;
    float* cbuf;
    _Float16* hf;
    float* hf32 = nullptr;
    int u0;
    if (blk < 64) {
        if (!(mask & 1)) return;
        xin = xin0; hp = hp0; wc = wc0; bb = bb0; cbuf = cb0; hf = ho0;
        u0 = blk * 16;
    } else {
        if (!(mask & 2)) return;
        xin = xin1; hp = hp1; wc = wc1; bb = bb1; cbuf = cb1; hf = ho1;
        hf32 = of1;
        u0 = (blk - 64) * 16;
    }

    const int lane = threadIdx.x & 63;
    const int wave = threadIdx.x >> 6;
    const int q = lane >> 4;
    const int m16 = lane & 15;
    const int r = wave * 16 + m16;

    f4_t acc[4] = {};
    const _Float16* wrow[4];
#pragma unroll
    for (int g = 0; g < 4; ++g)
        wrow[g] = wc + (size_t)(g * 1024 + u0 + m16) * 2048 + q * 8;

    {
        const _Float16* arow = xin + (size_t)r * 1024 + q * 8;
#pragma unroll 4
        for (int kk = 0; kk < 32; ++kk) {
            h8_t a = *(const h8_t*)(arow + kk * 32);
#pragma unroll
            for (int g = 0; g < 4; ++g) {
                h8_t b = *(const h8_t*)(wrow[g] + kk * 32);
                acc[g] = __builtin_amdgcn_mfma_f32_16x16x32_f16(a, b, acc[g], 0, 0, 0);
            }
        }
    }
    {
        const _Float16* arow = hp + (size_t)r * 1024 + q * 8;
#pragma unroll 4
        for (int kk = 0; kk < 32; ++kk) {
            h8_t a = *(const h8_t*)(arow + kk * 32);
#pragma unroll
            for (int g = 0; g < 4; ++g) {
                h8_t b = *(const h8_t*)(wrow[g] + 1024 + kk * 32);
                acc[g] = __builtin_amdgcn_mfma_f32_16x16x32_f16(a, b, acc[g], 0, 0, 0);
            }
        }
    }

    const int unit = u0 + m16;
    const float bi = bb[unit];
    const float bf = bb[1024 + unit];
    const float bg = bb[2048 + unit];
    const float bo = bb[3072 + unit];
#pragma unroll
    for (int ri = 0; ri < 4; ++ri) {
        int row = wave * 16 + q * 4 + ri;
        float iv = acc[0][ri] + bi;
        float fv = acc[1][ri] + bf;
        float gv = acc[2][ri] + bg;
        float ov = acc[3][ri] + bo;
        size_t idx = (size_t)row * HID + unit;
        float cn = sigmf(fv) * cbuf[idx] + sigmf(iv) * tanhf(gv);
        float hn = sigmf(ov) * tanhf(cn);
        cbuf[idx] = cn;
        hf[idx] = (_Float16)hn;
        if (hf32) hf32[idx] = hn;
    }
}

// ---------------- host orchestration ----------------

extern "C" void kernel_launch(void* const* d_in, const int* in_sizes, int n_in,
                              void* d_out, int out_size, void* d_ws, size_t ws_size,
                              hipStream_t stream) {
    const float* input = (const float*)d_in[0];
    const float* w_ih0 = (const float*)d_in[1];
    const float* w_hh0 = (const float*)d_in[2];
    const float* b_ih0 = (const float*)d_in[3];
    const float* b_hh0 = (const float*)d_in[4];
    const float* w_ih1 = (const float*)d_in[5];
    const float* w_hh1 = (const float*)d_in[6];
    const float* b_ih1 = (const float*)d_in[7];
    const float* b_hh1 = (const float*)d_in[8];
    float* outp = (float*)d_out;

    // workspace partition (~236 MB)
    char* p = (char*)d_ws;
    _Float16* x16 = (_Float16*)p;  p += (size_t)T_STEPS * STEP_ELEMS * 2;
    _Float16* h1  = (_Float16*)p;  p += (size_t)T_STEPS * STEP_ELEMS * 2;
    _Float16* h2  = (_Float16*)p;  p += (size_t)T_STEPS * STEP_ELEMS * 2;
    _Float16* wc0 = (_Float16*)p;  p += (size_t)4096 * 2048 * 2;
    _Float16* wc1 = (_Float16*)p;  p += (size_t)4096 * 2048 * 2;
    float* bias0  = (float*)p;     p += 4096 * 4;
    float* bias1  = (float*)p;     p += 4096 * 4;
    float* c0     = (float*)p;     p += STEP_ELEMS * 4;   // fallback only
    float* c1     = (float*)p;     p += STEP_ELEMS * 4;   // fallback only
    _Float16* hz  = (_Float16*)p;  p += STEP_ELEMS * 2;   // fallback only
    unsigned* cnt0 = (unsigned*)p; p += 256;
    unsigned* cnt1 = (unsigned*)p; p += 256;

    hipMemsetAsync(c0, 0, STEP_ELEMS * 4, stream);
    hipMemsetAsync(c1, 0, STEP_ELEMS * 4, stream);
    hipMemsetAsync(hz, 0, STEP_ELEMS * 2, stream);
    hipMemsetAsync(cnt0, 0, 512, stream);   // covers cnt0 + cnt1

    // conversions
    k_f32_to_f16<<<(T_STEPS * STEP_ELEMS / 4) / 256, 256, 0, stream>>>(input, x16);
    k_build_wcat<<<(4096 * 2048 / 4) / 256, 256, 0, stream>>>(w_ih0, w_hh0, wc0);
    k_build_wcat<<<(4096 * 2048 / 4) / 256, 256, 0, stream>>>(w_ih1, w_hh1, wc1);
    k_bias<<<16, 256, 0, stream>>>(b_ih0, b_hh0, bias0);
    k_bias<<<16, 256, 0, stream>>>(b_ih1, b_hh1, bias1);

    // persistent kernel: custom barriers inside, cooperative launch for residency
    void* params[] = { (void*)&x16, (void*)&h1, (void*)&h2, (void*)&outp,
                       (void*)&wc0, (void*)&wc1, (void*)&bias0, (void*)&bias1,
                       (void*)&cnt0, (void*)&cnt1 };
    hipError_t ce = hipLaunchCooperativeKernel((const void*)lstm_persist,
                                               dim3(256), dim3(256),
                                               params, 131072u, stream);
    if (ce != hipSuccess) {
        // fallback: per-step pipeline
        for (int s = 0; s <= T_STEPS; ++s) {
            int t1 = (s > 0) ? (s - 1) : 0;
            const _Float16* xin0 = x16 + (size_t)s * STEP_ELEMS;
            const _Float16* hp0  = (s == 0) ? hz : h1 + (size_t)(s - 1) * STEP_ELEMS;
            _Float16* ho0        = h1 + (size_t)s * STEP_ELEMS;
            const _Float16* xin1 = h1 + (size_t)t1 * STEP_ELEMS;
            const _Float16* hp1  = (t1 == 0) ? hz : h2 + (size_t)(t1 - 1) * STEP_ELEMS;
            _Float16* ho1        = h2 + (size_t)t1 * STEP_ELEMS;
            float* of1           = outp + (size_t)t1 * STEP_ELEMS;
            int mask = ((s < T_STEPS) ? 1 : 0) | ((s >= 1) ? 2 : 0);
            if (s == T_STEPS) xin0 = x16;
            lstm_step2<<<128, 256, 0, stream>>>(xin0, hp0, wc0, bias0, c0, ho0,
                                                xin1, hp1, wc1, bias1, c1, ho1,
                                                of1, mask);
        }
    }
}

// Round 3
// 7146.294 us; speedup vs baseline: 2.9639x; 2.5662x over previous
//
#include <hip/hip_runtime.h>

// LSTM_71167608094989: 2-layer LSTM, T=512, B=64, I=H=1024, eval mode.
// Round 4: fence-free persistent kernel.
//  - h published via agent-scope relaxed atomic stores (write-through; fresh
//    buffer per timestep => consumers can't hold stale lines), vmcnt(0) drain,
//    then per-block monotonic flag store (no RMW contention).
//  - Consumers poll 128 per-block flags with 128 lanes + __syncthreads_and,
//    then read h with PLAIN CACHED loads (L2 stays warm: no wbl2/inv ever).
//  - Compute loop: 2x4 chunked double-buffered A prefetch, even/odd split
//    accumulators (4 MFMA chains).

typedef _Float16 h8_t __attribute__((ext_vector_type(8)));
typedef _Float16 h4_t __attribute__((ext_vector_type(4)));
typedef float f4_t __attribute__((ext_vector_type(4)));

#define T_STEPS 512
#define BATCH 64
#define HID 1024
#define STEP_ELEMS (BATCH * HID)   // 65536

// ---------------- conversion kernels ----------------

__global__ void k_f32_to_f16(const float* __restrict__ src, _Float16* __restrict__ dst) {
    size_t i = ((size_t)blockIdx.x * blockDim.x + threadIdx.x) * 4;
    float4 v = *(const float4*)(src + i);
    h4_t h = { (_Float16)v.x, (_Float16)v.y, (_Float16)v.z, (_Float16)v.w };
    *(h4_t*)(dst + i) = h;
}

__global__ void k_build_wcat(const float* __restrict__ w_ih, const float* __restrict__ w_hh,
                             _Float16* __restrict__ wcat) {
    size_t i = ((size_t)blockIdx.x * blockDim.x + threadIdx.x) * 4;
    int n = (int)(i >> 11);
    int k = (int)(i & 2047);
    const float* src = (k < 1024) ? (w_ih + (size_t)n * 1024 + k)
                                  : (w_hh + (size_t)n * 1024 + (k - 1024));
    float4 v = *(const float4*)src;
    h4_t h = { (_Float16)v.x, (_Float16)v.y, (_Float16)v.z, (_Float16)v.w };
    *(h4_t*)(wcat + i) = h;
}

__global__ void k_bias(const float* __restrict__ a, const float* __restrict__ b,
                       float* __restrict__ o) {
    int i = blockIdx.x * blockDim.x + threadIdx.x;
    o[i] = a[i] + b[i];
}

__device__ __forceinline__ float sigmf(float x) { return 1.0f / (1.0f + __expf(-x)); }
__device__ __forceinline__ float tanh_fast(float x) {
    x = fminf(fmaxf(x, -15.f), 15.f);
    float e = __expf(2.f * x);
    return (e - 1.f) / (e + 1.f);
}

// ---------------- flag protocol (no fences, no RMW) ----------------

__device__ __forceinline__ void wait_flags(const unsigned* __restrict__ flags,
                                           unsigned target) {
    const int tid = threadIdx.x;
    for (;;) {
        unsigned v = target;
        if (tid < 128)
            v = __hip_atomic_load(&flags[tid], __ATOMIC_RELAXED,
                                  __HIP_MEMORY_SCOPE_AGENT);
        if (__syncthreads_and((int)(v >= target))) break;
        __builtin_amdgcn_s_sleep(1);
    }
}

__device__ __forceinline__ void publish_flag(unsigned* __restrict__ flag, unsigned val) {
    // all threads: drain own write-through h stores, then one flag store
    asm volatile("s_waitcnt vmcnt(0)" ::: "memory");
    __syncthreads();
    if (threadIdx.x == 0)
        __hip_atomic_store(flag, val, __ATOMIC_RELAXED, __HIP_MEMORY_SCOPE_AGENT);
}

// ---------------- persistent kernel ----------------
// grid = 256 blocks x 256 threads, dynamic LDS = 128 KB (swizzled weight slice).
// block b<128: layer0 units u0=b*8 ; b>=128: layer1 units u0=(b-128)*8.
// LDS: chunk(C,q) of kk at kk*2048 + ((q^(C&3))*512 + C*16).

__device__ __forceinline__ void do_phase(f4_t& a0e, f4_t& a0o, f4_t& a1e, f4_t& a1o,
                                         const _Float16* __restrict__ src, int aoff,
                                         const char* __restrict__ lb, int lds_base) {
    h8_t buf[2][4];
#pragma unroll
    for (int j = 0; j < 4; ++j)
        buf[0][j] = *(const h8_t*)(src + aoff + j * 32);
#pragma unroll
    for (int c = 0; c < 8; ++c) {
        if (c < 7) {
#pragma unroll
            for (int j = 0; j < 4; ++j)
                buf[(c + 1) & 1][j] = *(const h8_t*)(src + aoff + (c * 4 + 4 + j) * 32);
        }
#pragma unroll
        for (int j = 0; j < 4; ++j) {
            const int kk = c * 4 + j;
            h8_t b0 = *(const h8_t*)(lb + lds_base + kk * 2048);
            h8_t b1 = *(const h8_t*)(lb + lds_base + kk * 2048 + 256);
            if (kk & 1) {
                a0o = __builtin_amdgcn_mfma_f32_16x16x32_f16(buf[c & 1][j], b0, a0o, 0, 0, 0);
                a1o = __builtin_amdgcn_mfma_f32_16x16x32_f16(buf[c & 1][j], b1, a1o, 0, 0, 0);
            } else {
                a0e = __builtin_amdgcn_mfma_f32_16x16x32_f16(buf[c & 1][j], b0, a0e, 0, 0, 0);
                a1e = __builtin_amdgcn_mfma_f32_16x16x32_f16(buf[c & 1][j], b1, a1e, 0, 0, 0);
            }
        }
    }
}

__global__ __launch_bounds__(256, 1) void lstm_persist(
    const _Float16* __restrict__ x16, _Float16* __restrict__ h1,
    _Float16* __restrict__ h2, float* __restrict__ out,
    const _Float16* __restrict__ wc0, const _Float16* __restrict__ wc1,
    const float* __restrict__ bias0, const float* __restrict__ bias1,
    unsigned* __restrict__ f0, unsigned* __restrict__ f1)
{
    extern __shared__ char smem[];
    const int blk = blockIdx.x;
    const int layer = blk >> 7;
    const int u0 = (blk & 127) * 8;
    const _Float16* __restrict__ wc = layer ? wc1 : wc0;
    const float* __restrict__ bias = layer ? bias1 : bias0;
    const int tid = threadIdx.x;

    // one-time staging: coalesced global reads, swizzled LDS writes
    {
        const int kk = tid >> 2, qq = tid & 3;
#pragma unroll 4
        for (int C = 0; C < 32; ++C) {
            const int n = ((C >> 3) << 10) + u0 + (C & 7);
            h8_t v = *(const h8_t*)(wc + (size_t)n * 2048 + (size_t)kk * 32 + qq * 8);
            const int p = qq ^ (C & 3);
            *(h8_t*)(smem + kk * 2048 + p * 512 + C * 16) = v;
        }
    }
    __syncthreads();

    const int lane = tid & 63;
    const int wave = tid >> 6;
    const int q = lane >> 4;
    const int m16 = lane & 15;
    const int unit = u0 + (m16 & 7);
    const bool lo8 = (m16 & 8) == 0;

    const float bi = bias[unit];
    const float bf = bias[1024 + unit];
    const float bg = bias[2048 + unit];
    const float bo = bias[3072 + unit];

    const char* __restrict__ lb = smem + ((q ^ (m16 & 3)) * 512 + m16 * 16);
    const int aoff = (wave * 16 + m16) * 1024 + q * 8;

    float cst[4] = {0.f, 0.f, 0.f, 0.f};

    if (layer == 0) {
        unsigned* myflag = &f0[blk];
        for (int s = 0; s < T_STEPS; ++s) {
            f4_t a0e = {0.f,0.f,0.f,0.f}, a0o = {0.f,0.f,0.f,0.f};
            f4_t a1e = {0.f,0.f,0.f,0.f}, a1o = {0.f,0.f,0.f,0.f};
            // phase 1: x[s] — no dependency, overlaps other blocks' step s-1
            do_phase(a0e, a0o, a1e, a1o, x16 + (size_t)s * STEP_ELEMS, aoff, lb, 0);
            if (s) {
                wait_flags(f0, (unsigned)s);          // h1[s-1] complete (all blocks)
                do_phase(a0e, a0o, a1e, a1o,
                         h1 + (size_t)(s - 1) * STEP_ELEMS, aoff, lb, 65536);
            }
            const f4_t acc0 = a0e + a0o;
            const f4_t acc1 = a1e + a1o;
            _Float16* __restrict__ hout = h1 + (size_t)s * STEP_ELEMS;
#pragma unroll
            for (int ri = 0; ri < 4; ++ri) {
                const float p0 = __shfl_xor(acc0[ri], 8, 64);
                const float p1 = __shfl_xor(acc1[ri], 8, 64);
                const float iv = (lo8 ? acc0[ri] : p0) + bi;
                const float fv = (lo8 ? p0 : acc0[ri]) + bf;
                const float gv = (lo8 ? acc1[ri] : p1) + bg;
                const float ov = (lo8 ? p1 : acc1[ri]) + bo;
                const float cn = sigmf(fv) * cst[ri] + sigmf(iv) * tanh_fast(gv);
                const float hn = sigmf(ov) * tanh_fast(cn);
                cst[ri] = cn;
                if (lo8) {
                    const size_t idx = (size_t)((wave * 16 + q * 4 + ri) * HID + unit);
                    const unsigned short hb =
                        __builtin_bit_cast(unsigned short, (_Float16)hn);
                    __hip_atomic_store((unsigned short*)(hout + idx), hb,
                                       __ATOMIC_RELAXED, __HIP_MEMORY_SCOPE_AGENT);
                }
            }
            publish_flag(myflag, (unsigned)(s + 1));
        }
    } else {
        unsigned* myflag = &f1[blk & 127];
        for (int t = 0; t < T_STEPS; ++t) {
            wait_flags(f0, (unsigned)(t + 1));        // h1[t] ready (L0 runs ahead)
            if (t) wait_flags(f1, (unsigned)t);       // h2[t-1] complete
            f4_t a0e = {0.f,0.f,0.f,0.f}, a0o = {0.f,0.f,0.f,0.f};
            f4_t a1e = {0.f,0.f,0.f,0.f}, a1o = {0.f,0.f,0.f,0.f};
            do_phase(a0e, a0o, a1e, a1o, h1 + (size_t)t * STEP_ELEMS, aoff, lb, 0);
            if (t)
                do_phase(a0e, a0o, a1e, a1o,
                         h2 + (size_t)(t - 1) * STEP_ELEMS, aoff, lb, 65536);
            const f4_t acc0 = a0e + a0o;
            const f4_t acc1 = a1e + a1o;
            _Float16* __restrict__ hout = h2 + (size_t)t * STEP_ELEMS;
            float* __restrict__ oout = out + (size_t)t * STEP_ELEMS;
#pragma unroll
            for (int ri = 0; ri < 4; ++ri) {
                const float p0 = __shfl_xor(acc0[ri], 8, 64);
                const float p1 = __shfl_xor(acc1[ri], 8, 64);
                const float iv = (lo8 ? acc0[ri] : p0) + bi;
                const float fv = (lo8 ? p0 : acc0[ri]) + bf;
                const float gv = (lo8 ? acc1[ri] : p1) + bg;
                const float ov = (lo8 ? p1 : acc1[ri]) + bo;
                const float cn = sigmf(fv) * cst[ri] + sigmf(iv) * tanh_fast(gv);
                const float hn = sigmf(ov) * tanh_fast(cn);
                cst[ri] = cn;
                if (lo8) {
                    const size_t idx = (size_t)((wave * 16 + q * 4 + ri) * HID + unit);
                    const unsigned short hb =
                        __builtin_bit_cast(unsigned short, (_Float16)hn);
                    __hip_atomic_store((unsigned short*)(hout + idx), hb,
                                       __ATOMIC_RELAXED, __HIP_MEMORY_SCOPE_AGENT);
                    oout[idx] = hn;   // plain store; kernel-end release covers host read
                }
            }
            publish_flag(myflag, (unsigned)(t + 1));
        }
    }
}

// ---------------- fallback per-step kernel (safety) ----------------

__global__ __launch_bounds__(256) void lstm_step2(
    const _Float16* __restrict__ xin0, const _Float16* __restrict__ hp0,
    const _Float16* __restrict__ wc0, const float* __restrict__ bb0,
    float* __restrict__ cb0, _Float16* __restrict__ ho0,
    const _Float16* __restrict__ xin1, const _Float16* __restrict__ hp1,
    const _Float16* __restrict__ wc1, const float* __restrict__ bb1,
    float* __restrict__ cb1, _Float16* __restrict__ ho1,
    float* __restrict__ of1, int mask)
{
    int blk = blockIdx.x;
    const _Float16 *xin, *hp, *wc;
    const float* bb;
    float* cbuf;
    _Float16* hf;
    float* hf32 = nullptr;
    int u0;
    if (blk < 64) {
        if (!(mask & 1)) return;
        xin = xin0; hp = hp0; wc = wc0; bb = bb0; cbuf = cb0; hf = ho0;
        u0 = blk * 16;
    } else {
        if (!(mask & 2)) return;
        xin = xin1; hp = hp1; wc = wc1; bb = bb1; cbuf = cb1; hf = ho1;
        hf32 = of1;
        u0 = (blk - 64) * 16;
    }

    const int lane = threadIdx.x & 63;
    const int wave = threadIdx.x >> 6;
    const int q = lane >> 4;
    const int m16 = lane & 15;
    const int r = wave * 16 + m16;

    f4_t acc[4] = {};
    const _Float16* wrow[4];
#pragma unroll
    for (int g = 0; g < 4; ++g)
        wrow[g] = wc + (size_t)(g * 1024 + u0 + m16) * 2048 + q * 8;

    {
        const _Float16* arow = xin + (size_t)r * 1024 + q * 8;
#pragma unroll 4
        for (int kk = 0; kk < 32; ++kk) {
            h8_t a = *(const h8_t*)(arow + kk * 32);
#pragma unroll
            for (int g = 0; g < 4; ++g) {
                h8_t b = *(const h8_t*)(wrow[g] + kk * 32);
                acc[g] = __builtin_amdgcn_mfma_f32_16x16x32_f16(a, b, acc[g], 0, 0, 0);
            }
        }
    }
    {
        const _Float16* arow = hp + (size_t)r * 1024 + q * 8;
#pragma unroll 4
        for (int kk = 0; kk < 32; ++kk) {
            h8_t a = *(const h8_t*)(arow + kk * 32);
#pragma unroll
            for (int g = 0; g < 4; ++g) {
                h8_t b = *(const h8_t*)(wrow[g] + 1024 + kk * 32);
                acc[g] = __builtin_amdgcn_mfma_f32_16x16x32_f16(a, b, acc[g], 0, 0, 0);
            }
        }
    }

    const int unit = u0 + m16;
    const float bi = bb[unit];
    const float bf = bb[1024 + unit];
    const float bg = bb[2048 + unit];
    const float bo = bb[3072 + unit];
#pragma unroll
    for (int ri = 0; ri < 4; ++ri) {
        int row = wave * 16 + q * 4 + ri;
        float iv = acc[0][ri] + bi;
        float fv = acc[1][ri] + bf;
        float gv = acc[2][ri] + bg;
        float ov = acc[3][ri] + bo;
        size_t idx = (size_t)row * HID + unit;
        float cn = sigmf(fv) * cbuf[idx] + sigmf(iv) * tanhf(gv);
        float hn = sigmf(ov) * tanhf(cn);
        cbuf[idx] = cn;
        hf[idx] = (_Float16)hn;
        if (hf32) hf32[idx] = hn;
    }
}

// ---------------- host orchestration ----------------

extern "C" void kernel_launch(void* const* d_in, const int* in_sizes, int n_in,
                              void* d_out, int out_size, void* d_ws, size_t ws_size,
                              hipStream_t stream) {
    const float* input = (const float*)d_in[0];
    const float* w_ih0 = (const float*)d_in[1];
    const float* w_hh0 = (const float*)d_in[2];
    const float* b_ih0 = (const float*)d_in[3];
    const float* b_hh0 = (const float*)d_in[4];
    const float* w_ih1 = (const float*)d_in[5];
    const float* w_hh1 = (const float*)d_in[6];
    const float* b_ih1 = (const float*)d_in[7];
    const float* b_hh1 = (const float*)d_in[8];
    float* outp = (float*)d_out;

    // workspace partition (~236 MB)
    char* p = (char*)d_ws;
    _Float16* x16 = (_Float16*)p;  p += (size_t)T_STEPS * STEP_ELEMS * 2;
    _Float16* h1  = (_Float16*)p;  p += (size_t)T_STEPS * STEP_ELEMS * 2;
    _Float16* h2  = (_Float16*)p;  p += (size_t)T_STEPS * STEP_ELEMS * 2;
    _Float16* wc0 = (_Float16*)p;  p += (size_t)4096 * 2048 * 2;
    _Float16* wc1 = (_Float16*)p;  p += (size_t)4096 * 2048 * 2;
    float* bias0  = (float*)p;     p += 4096 * 4;
    float* bias1  = (float*)p;     p += 4096 * 4;
    float* c0     = (float*)p;     p += STEP_ELEMS * 4;   // fallback only
    float* c1     = (float*)p;     p += STEP_ELEMS * 4;   // fallback only
    _Float16* hz  = (_Float16*)p;  p += STEP_ELEMS * 2;   // fallback only
    unsigned* f0  = (unsigned*)p;  p += 512;              // 128 flags, layer0
    unsigned* f1  = (unsigned*)p;  p += 512;              // 128 flags, layer1

    hipMemsetAsync(c0, 0, STEP_ELEMS * 4, stream);
    hipMemsetAsync(c1, 0, STEP_ELEMS * 4, stream);
    hipMemsetAsync(hz, 0, STEP_ELEMS * 2, stream);
    hipMemsetAsync(f0, 0, 1024, stream);   // f0 + f1

    // conversions
    k_f32_to_f16<<<(T_STEPS * STEP_ELEMS / 4) / 256, 256, 0, stream>>>(input, x16);
    k_build_wcat<<<(4096 * 2048 / 4) / 256, 256, 0, stream>>>(w_ih0, w_hh0, wc0);
    k_build_wcat<<<(4096 * 2048 / 4) / 256, 256, 0, stream>>>(w_ih1, w_hh1, wc1);
    k_bias<<<16, 256, 0, stream>>>(b_ih0, b_hh0, bias0);
    k_bias<<<16, 256, 0, stream>>>(b_ih1, b_hh1, bias1);

    // persistent kernel: cooperative launch for guaranteed co-residency
    void* params[] = { (void*)&x16, (void*)&h1, (void*)&h2, (void*)&outp,
                       (void*)&wc0, (void*)&wc1, (void*)&bias0, (void*)&bias1,
                       (void*)&f0, (void*)&f1 };
    hipError_t ce = hipLaunchCooperativeKernel((const void*)lstm_persist,
                                               dim3(256), dim3(256),
                                               params, 131072u, stream);
    if (ce != hipSuccess) {
        // fallback: per-step pipeline
        for (int s = 0; s <= T_STEPS; ++s) {
            int t1 = (s > 0) ? (s - 1) : 0;
            const _Float16* xin0 = x16 + (size_t)s * STEP_ELEMS;
            const _Float16* hp0  = (s == 0) ? hz : h1 + (size_t)(s - 1) * STEP_ELEMS;
            _Float16* ho0        = h1 + (size_t)s * STEP_ELEMS;
            const _Float16* xin1 = h1 + (size_t)t1 * STEP_ELEMS;
            const _Float16* hp1  = (t1 == 0) ? hz : h2 + (size_t)(t1 - 1) * STEP_ELEMS;
            _Float16* ho1        = h2 + (size_t)t1 * STEP_ELEMS;
            float* of1           = outp + (size_t)t1 * STEP_ELEMS;
            int mask = ((s < T_STEPS) ? 1 : 0) | ((s >= 1) ? 2 : 0);
            if (s == T_STEPS) xin0 = x16;
            lstm_step2<<<128, 256, 0, stream>>>(xin0, hp0, wc0, bias0, c0, ho0,
                                                xin1, hp1, wc1, bias1, c1, ho1,
                                                of1, mask);
        }
    }
}

// Round 4
// 7139.692 us; speedup vs baseline: 2.9667x; 1.0009x over previous
//
#include <hip/hip_runtime.h>

// LSTM_71167608094989: 2-layer LSTM, T=512, B=64, I=H=1024, eval mode.
// Round 5: fence-free persistent kernel (round-4 protocol) + full-depth
// 32-load A-prefetch per phase (round-4's 4-deep chunking capped MLP at 4
// outstanding loads -> ~2.3us/phase latency serialization; this restores
// 32-deep issue, one exposed latency per phase).

typedef _Float16 h8_t __attribute__((ext_vector_type(8)));
typedef _Float16 h4_t __attribute__((ext_vector_type(4)));
typedef float f4_t __attribute__((ext_vector_type(4)));

#define T_STEPS 512
#define BATCH 64
#define HID 1024
#define STEP_ELEMS (BATCH * HID)   // 65536

// ---------------- conversion kernels ----------------

__global__ void k_f32_to_f16(const float* __restrict__ src, _Float16* __restrict__ dst) {
    size_t i = ((size_t)blockIdx.x * blockDim.x + threadIdx.x) * 4;
    float4 v = *(const float4*)(src + i);
    h4_t h = { (_Float16)v.x, (_Float16)v.y, (_Float16)v.z, (_Float16)v.w };
    *(h4_t*)(dst + i) = h;
}

__global__ void k_build_wcat(const float* __restrict__ w_ih, const float* __restrict__ w_hh,
                             _Float16* __restrict__ wcat) {
    size_t i = ((size_t)blockIdx.x * blockDim.x + threadIdx.x) * 4;
    int n = (int)(i >> 11);
    int k = (int)(i & 2047);
    const float* src = (k < 1024) ? (w_ih + (size_t)n * 1024 + k)
                                  : (w_hh + (size_t)n * 1024 + (k - 1024));
    float4 v = *(const float4*)src;
    h4_t h = { (_Float16)v.x, (_Float16)v.y, (_Float16)v.z, (_Float16)v.w };
    *(h4_t*)(wcat + i) = h;
}

__global__ void k_bias(const float* __restrict__ a, const float* __restrict__ b,
                       float* __restrict__ o) {
    int i = blockIdx.x * blockDim.x + threadIdx.x;
    o[i] = a[i] + b[i];
}

__device__ __forceinline__ float sigmf(float x) { return 1.0f / (1.0f + __expf(-x)); }
__device__ __forceinline__ float tanh_fast(float x) {
    x = fminf(fmaxf(x, -15.f), 15.f);
    float e = __expf(2.f * x);
    return (e - 1.f) / (e + 1.f);
}

// ---------------- flag protocol (no fences, no RMW) ----------------

__device__ __forceinline__ void wait_flags(const unsigned* __restrict__ flags,
                                           unsigned target) {
    const int tid = threadIdx.x;
    for (;;) {
        unsigned v = target;
        if (tid < 128)
            v = __hip_atomic_load(&flags[tid], __ATOMIC_RELAXED,
                                  __HIP_MEMORY_SCOPE_AGENT);
        if (__syncthreads_and((int)(v >= target))) break;
        __builtin_amdgcn_s_sleep(1);
    }
}

__device__ __forceinline__ void publish_flag(unsigned* __restrict__ flag, unsigned val) {
    // all threads: drain own write-through h stores, then one flag store
    asm volatile("s_waitcnt vmcnt(0)" ::: "memory");
    __syncthreads();
    if (threadIdx.x == 0)
        __hip_atomic_store(flag, val, __ATOMIC_RELAXED, __HIP_MEMORY_SCOPE_AGENT);
}

// ---------------- compute helpers ----------------
// LDS: chunk(C,q) of kk at kk*2048 + ((q^(C&3))*512 + C*16).

__device__ __forceinline__ void issue32(h8_t* __restrict__ areg,
                                        const _Float16* __restrict__ src, int aoff) {
#pragma unroll
    for (int kk = 0; kk < 32; ++kk)
        areg[kk] = *(const h8_t*)(src + aoff + kk * 32);
}

__device__ __forceinline__ void mfma32(f4_t& a0e, f4_t& a0o, f4_t& a1e, f4_t& a1o,
                                       const h8_t* __restrict__ areg,
                                       const char* __restrict__ lb, int lds_base) {
#pragma unroll
    for (int kk = 0; kk < 32; ++kk) {
        h8_t b0 = *(const h8_t*)(lb + lds_base + kk * 2048);
        h8_t b1 = *(const h8_t*)(lb + lds_base + kk * 2048 + 256);
        if (kk & 1) {
            a0o = __builtin_amdgcn_mfma_f32_16x16x32_f16(areg[kk], b0, a0o, 0, 0, 0);
            a1o = __builtin_amdgcn_mfma_f32_16x16x32_f16(areg[kk], b1, a1o, 0, 0, 0);
        } else {
            a0e = __builtin_amdgcn_mfma_f32_16x16x32_f16(areg[kk], b0, a0e, 0, 0, 0);
            a1e = __builtin_amdgcn_mfma_f32_16x16x32_f16(areg[kk], b1, a1e, 0, 0, 0);
        }
    }
}

// ---------------- persistent kernel ----------------
// grid = 256 blocks x 256 threads, dynamic LDS = 128 KB (swizzled weight slice).
// block b<128: layer0 units u0=b*8 ; b>=128: layer1 units u0=(b-128)*8.

__global__ __launch_bounds__(256, 1) void lstm_persist(
    const _Float16* __restrict__ x16, _Float16* __restrict__ h1,
    _Float16* __restrict__ h2, float* __restrict__ out,
    const _Float16* __restrict__ wc0, const _Float16* __restrict__ wc1,
    const float* __restrict__ bias0, const float* __restrict__ bias1,
    unsigned* __restrict__ f0, unsigned* __restrict__ f1)
{
    extern __shared__ char smem[];
    const int blk = blockIdx.x;
    const int layer = blk >> 7;
    const int u0 = (blk & 127) * 8;
    const _Float16* __restrict__ wc = layer ? wc1 : wc0;
    const float* __restrict__ bias = layer ? bias1 : bias0;
    const int tid = threadIdx.x;

    // one-time staging: coalesced global reads, swizzled LDS writes
    {
        const int kk = tid >> 2, qq = tid & 3;
#pragma unroll 4
        for (int C = 0; C < 32; ++C) {
            const int n = ((C >> 3) << 10) + u0 + (C & 7);
            h8_t v = *(const h8_t*)(wc + (size_t)n * 2048 + (size_t)kk * 32 + qq * 8);
            const int p = qq ^ (C & 3);
            *(h8_t*)(smem + kk * 2048 + p * 512 + C * 16) = v;
        }
    }
    __syncthreads();

    const int lane = tid & 63;
    const int wave = tid >> 6;
    const int q = lane >> 4;
    const int m16 = lane & 15;
    const int unit = u0 + (m16 & 7);
    const bool lo8 = (m16 & 8) == 0;

    const float bi = bias[unit];
    const float bf = bias[1024 + unit];
    const float bg = bias[2048 + unit];
    const float bo = bias[3072 + unit];

    const char* __restrict__ lb = smem + ((q ^ (m16 & 3)) * 512 + m16 * 16);
    const int aoff = (wave * 16 + m16) * 1024 + q * 8;

    float cst[4] = {0.f, 0.f, 0.f, 0.f};

    if (layer == 0) {
        unsigned* myflag = &f0[blk];
        for (int s = 0; s < T_STEPS; ++s) {
            h8_t areg[32];
            f4_t a0e = {0.f,0.f,0.f,0.f}, a0o = {0.f,0.f,0.f,0.f};
            f4_t a1e = {0.f,0.f,0.f,0.f}, a1o = {0.f,0.f,0.f,0.f};
            // phase 1: x[s] — issue all 32 loads, consume in order
            issue32(areg, x16 + (size_t)s * STEP_ELEMS, aoff);
            mfma32(a0e, a0o, a1e, a1o, areg, lb, 0);
            if (s) {
                wait_flags(f0, (unsigned)s);          // h1[s-1] complete (all blocks)
                issue32(areg, h1 + (size_t)(s - 1) * STEP_ELEMS, aoff);
                mfma32(a0e, a0o, a1e, a1o, areg, lb, 65536);
            }
            const f4_t acc0 = a0e + a0o;
            const f4_t acc1 = a1e + a1o;
            _Float16* __restrict__ hout = h1 + (size_t)s * STEP_ELEMS;
#pragma unroll
            for (int ri = 0; ri < 4; ++ri) {
                const float p0 = __shfl_xor(acc0[ri], 8, 64);
                const float p1 = __shfl_xor(acc1[ri], 8, 64);
                const float iv = (lo8 ? acc0[ri] : p0) + bi;
                const float fv = (lo8 ? p0 : acc0[ri]) + bf;
                const float gv = (lo8 ? acc1[ri] : p1) + bg;
                const float ov = (lo8 ? p1 : acc1[ri]) + bo;
                const float cn = sigmf(fv) * cst[ri] + sigmf(iv) * tanh_fast(gv);
                const float hn = sigmf(ov) * tanh_fast(cn);
                cst[ri] = cn;
                if (lo8) {
                    const size_t idx = (size_t)((wave * 16 + q * 4 + ri) * HID + unit);
                    const unsigned short hb =
                        __builtin_bit_cast(unsigned short, (_Float16)hn);
                    __hip_atomic_store((unsigned short*)(hout + idx), hb,
                                       __ATOMIC_RELAXED, __HIP_MEMORY_SCOPE_AGENT);
                }
            }
            publish_flag(myflag, (unsigned)(s + 1));
        }
    } else {
        unsigned* myflag = &f1[blk & 127];
        for (int t = 0; t < T_STEPS; ++t) {
            h8_t areg[32];
            f4_t a0e = {0.f,0.f,0.f,0.f}, a0o = {0.f,0.f,0.f,0.f};
            f4_t a1e = {0.f,0.f,0.f,0.f}, a1o = {0.f,0.f,0.f,0.f};
            wait_flags(f0, (unsigned)(t + 1));        // h1[t] ready (L0 runs ahead)
            issue32(areg, h1 + (size_t)t * STEP_ELEMS, aoff);
            mfma32(a0e, a0o, a1e, a1o, areg, lb, 0);
            if (t) {
                wait_flags(f1, (unsigned)t);          // h2[t-1] complete
                issue32(areg, h2 + (size_t)(t - 1) * STEP_ELEMS, aoff);
                mfma32(a0e, a0o, a1e, a1o, areg, lb, 65536);
            }
            const f4_t acc0 = a0e + a0o;
            const f4_t acc1 = a1e + a1o;
            _Float16* __restrict__ hout = h2 + (size_t)t * STEP_ELEMS;
            float* __restrict__ oout = out + (size_t)t * STEP_ELEMS;
#pragma unroll
            for (int ri = 0; ri < 4; ++ri) {
                const float p0 = __shfl_xor(acc0[ri], 8, 64);
                const float p1 = __shfl_xor(acc1[ri], 8, 64);
                const float iv = (lo8 ? acc0[ri] : p0) + bi;
                const float fv = (lo8 ? p0 : acc0[ri]) + bf;
                const float gv = (lo8 ? acc1[ri] : p1) + bg;
                const float ov = (lo8 ? p1 : acc1[ri]) + bo;
                const float cn = sigmf(fv) * cst[ri] + sigmf(iv) * tanh_fast(gv);
                const float hn = sigmf(ov) * tanh_fast(cn);
                cst[ri] = cn;
                if (lo8) {
                    const size_t idx = (size_t)((wave * 16 + q * 4 + ri) * HID + unit);
                    const unsigned short hb =
                        __builtin_bit_cast(unsigned short, (_Float16)hn);
                    __hip_atomic_store((unsigned short*)(hout + idx), hb,
                                       __ATOMIC_RELAXED, __HIP_MEMORY_SCOPE_AGENT);
                    oout[idx] = hn;   // plain store; kernel-end release covers host read
                }
            }
            publish_flag(myflag, (unsigned)(t + 1));
        }
    }
}

// ---------------- fallback per-step kernel (safety) ----------------

__global__ __launch_bounds__(256) void lstm_step2(
    const _Float16* __restrict__ xin0, const _Float16* __restrict__ hp0,
    const _Float16* __restrict__ wc0, const float* __restrict__ bb0,
    float* __restrict__ cb0, _Float16* __restrict__ ho0,
    const _Float16* __restrict__ xin1, const _Float16* __restrict__ hp1,
    const _Float16* __restrict__ wc1, const float* __restrict__ bb1,
    float* __restrict__ cb1, _Float16* __restrict__ ho1,
    float* __restrict__ of1, int mask)
{
    int blk = blockIdx.x;
    const _Float16 *xin, *hp, *wc;
    const float* bb;
    float* cbuf;
    _Float16* hf;
    float* hf32 = nullptr;
    int u0;
    if (blk < 64) {
        if (!(mask & 1)) return;
        xin = xin0; hp = hp0; wc = wc0; bb = bb0; cbuf = cb0; hf = ho0;
        u0 = blk * 16;
    } else {
        if (!(mask & 2)) return;
        xin = xin1; hp = hp1; wc = wc1; bb = bb1; cbuf = cb1; hf = ho1;
        hf32 = of1;
        u0 = (blk - 64) * 16;
    }

    const int lane = threadIdx.x & 63;
    const int wave = threadIdx.x >> 6;
    const int q = lane >> 4;
    const int m16 = lane & 15;
    const int r = wave * 16 + m16;

    f4_t acc[4] = {};
    const _Float16* wrow[4];
#pragma unroll
    for (int g = 0; g < 4; ++g)
        wrow[g] = wc + (size_t)(g * 1024 + u0 + m16) * 2048 + q * 8;

    {
        const _Float16* arow = xin + (size_t)r * 1024 + q * 8;
#pragma unroll 4
        for (int kk = 0; kk < 32; ++kk) {
            h8_t a = *(const h8_t*)(arow + kk * 32);
#pragma unroll
            for (int g = 0; g < 4; ++g) {
                h8_t b = *(const h8_t*)(wrow[g] + kk * 32);
                acc[g] = __builtin_amdgcn_mfma_f32_16x16x32_f16(a, b, acc[g], 0, 0, 0);
            }
        }
    }
    {
        const _Float16* arow = hp + (size_t)r * 1024 + q * 8;
#pragma unroll 4
        for (int kk = 0; kk < 32; ++kk) {
            h8_t a = *(const h8_t*)(arow + kk * 32);
#pragma unroll
            for (int g = 0; g < 4; ++g) {
                h8_t b = *(const h8_t*)(wrow[g] + 1024 + kk * 32);
                acc[g] = __builtin_amdgcn_mfma_f32_16x16x32_f16(a, b, acc[g], 0, 0, 0);
            }
        }
    }

    const int unit = u0 + m16;
    const float bi = bb[unit];
    const float bf = bb[1024 + unit];
    const float bg = bb[2048 + unit];
    const float bo = bb[3072 + unit];
#pragma unroll
    for (int ri = 0; ri < 4; ++ri) {
        int row = wave * 16 + q * 4 + ri;
        float iv = acc[0][ri] + bi;
        float fv = acc[1][ri] + bf;
        float gv = acc[2][ri] + bg;
        float ov = acc[3][ri] + bo;
        size_t idx = (size_t)row * HID + unit;
        float cn = sigmf(fv) * cbuf[idx] + sigmf(iv) * tanhf(gv);
        float hn = sigmf(ov) * tanhf(cn);
        cbuf[idx] = cn;
        hf[idx] = (_Float16)hn;
        if (hf32) hf32[idx] = hn;
    }
}

// ---------------- host orchestration ----------------

extern "C" void kernel_launch(void* const* d_in, const int* in_sizes, int n_in,
                              void* d_out, int out_size, void* d_ws, size_t ws_size,
                              hipStream_t stream) {
    const float* input = (const float*)d_in[0];
    const float* w_ih0 = (const float*)d_in[1];
    const float* w_hh0 = (const float*)d_in[2];
    const float* b_ih0 = (const float*)d_in[3];
    const float* b_hh0 = (const float*)d_in[4];
    const float* w_ih1 = (const float*)d_in[5];
    const float* w_hh1 = (const float*)d_in[6];
    const float* b_ih1 = (const float*)d_in[7];
    const float* b_hh1 = (const float*)d_in[8];
    float* outp = (float*)d_out;

    // workspace partition (~236 MB)
    char* p = (char*)d_ws;
    _Float16* x16 = (_Float16*)p;  p += (size_t)T_STEPS * STEP_ELEMS * 2;
    _Float16* h1  = (_Float16*)p;  p += (size_t)T_STEPS * STEP_ELEMS * 2;
    _Float16* h2  = (_Float16*)p;  p += (size_t)T_STEPS * STEP_ELEMS * 2;
    _Float16* wc0 = (_Float16*)p;  p += (size_t)4096 * 2048 * 2;
    _Float16* wc1 = (_Float16*)p;  p += (size_t)4096 * 2048 * 2;
    float* bias0  = (float*)p;     p += 4096 * 4;
    float* bias1  = (float*)p;     p += 4096 * 4;
    float* c0     = (float*)p;     p += STEP_ELEMS * 4;   // fallback only
    float* c1     = (float*)p;     p += STEP_ELEMS * 4;   // fallback only
    _Float16* hz  = (_Float16*)p;  p += STEP_ELEMS * 2;   // fallback only
    unsigned* f0  = (unsigned*)p;  p += 512;              // 128 flags, layer0
    unsigned* f1  = (unsigned*)p;  p += 512;              // 128 flags, layer1

    hipMemsetAsync(c0, 0, STEP_ELEMS * 4, stream);
    hipMemsetAsync(c1, 0, STEP_ELEMS * 4, stream);
    hipMemsetAsync(hz, 0, STEP_ELEMS * 2, stream);
    hipMemsetAsync(f0, 0, 1024, stream);   // f0 + f1

    // conversions
    k_f32_to_f16<<<(T_STEPS * STEP_ELEMS / 4) / 256, 256, 0, stream>>>(input, x16);
    k_build_wcat<<<(4096 * 2048 / 4) / 256, 256, 0, stream>>>(w_ih0, w_hh0, wc0);
    k_build_wcat<<<(4096 * 2048 / 4) / 256, 256, 0, stream>>>(w_ih1, w_hh1, wc1);
    k_bias<<<16, 256, 0, stream>>>(b_ih0, b_hh0, bias0);
    k_bias<<<16, 256, 0, stream>>>(b_ih1, b_hh1, bias1);

    // persistent kernel: cooperative launch for guaranteed co-residency
    void* params[] = { (void*)&x16, (void*)&h1, (void*)&h2, (void*)&outp,
                       (void*)&wc0, (void*)&wc1, (void*)&bias0, (void*)&bias1,
                       (void*)&f0, (void*)&f1 };
    hipError_t ce = hipLaunchCooperativeKernel((const void*)lstm_persist,
                                               dim3(256), dim3(256),
                                               params, 131072u, stream);
    if (ce != hipSuccess) {
        // fallback: per-step pipeline
        for (int s = 0; s <= T_STEPS; ++s) {
            int t1 = (s > 0) ? (s - 1) : 0;
            const _Float16* xin0 = x16 + (size_t)s * STEP_ELEMS;
            const _Float16* hp0  = (s == 0) ? hz : h1 + (size_t)(s - 1) * STEP_ELEMS;
            _Float16* ho0        = h1 + (size_t)s * STEP_ELEMS;
            const _Float16* xin1 = h1 + (size_t)t1 * STEP_ELEMS;
            const _Float16* hp1  = (t1 == 0) ? hz : h2 + (size_t)(t1 - 1) * STEP_ELEMS;
            _Float16* ho1        = h2 + (size_t)t1 * STEP_ELEMS;
            float* of1           = outp + (size_t)t1 * STEP_ELEMS;
            int mask = ((s < T_STEPS) ? 1 : 0) | ((s >= 1) ? 2 : 0);
            if (s == T_STEPS) xin0 = x16;
            lstm_step2<<<128, 256, 0, stream>>>(xin0, hp0, wc0, bias0, c0, ho0,
                                                xin1, hp1, wc1, bias1, c1, ho1,
                                                of1, mask);
        }
    }
}